// Round 2
// baseline (146.134 us; speedup 1.0000x reference)
//
#include <hip/hip_runtime.h>

#define NUM_GRAPHS 128
#define NUM_T 64
#define NUM_S 64
#define CHUNKS 2

// starts[g] = first index n with batch[n] >= g, g in [0, NUM_GRAPHS].
__global__ void seg_starts_kernel(const int* __restrict__ batch, int n,
                                  int* __restrict__ starts) {
    int g = threadIdx.x;
    if (g > NUM_GRAPHS) return;
    int lo = 0, hi = n;
    while (lo < hi) {
        int mid = (lo + hi) >> 1;
        if (batch[mid] < g) lo = mid + 1; else hi = mid;
    }
    starts[g] = lo;
}

// Windowed-sigmoid ECT. sigmoid(200*(lin_s - nh)) is ~0 / ~1 outside
// |lin_s - nh| <= 0.05 (|z|<=10, tail <= 4.5e-5). lin spacing = 2/63, so at
// most 4 consecutive s need exact evaluation. Per (point,t):
//   s_w = ceil((nh + 0.95) * 31.5)           (first s with z >= -10)
//   bins[s][t] += sigmoid exact, s in [s_w, s_w+4) ∩ [0,64)
//   cnt[clamp(s_w+4,0,64)][t] += 1           (all s >= s_w+4 contribute 1.0)
// out[s][t] = bins[s][t] + sum_{c<=s} cnt[c][t].
__global__ __launch_bounds__(512, 1) void ect_window_kernel(
    const float2* __restrict__ x, const float* __restrict__ v,
    const int* __restrict__ starts, float* __restrict__ out)
{
    constexpr float K  = 288.53900817779268f;  // 200 * log2(e)
    constexpr float KD = 9.1599685135807200f;  // K * (2/63)
    const int g     = blockIdx.x;
    const int chunk = blockIdx.y;
    const int tid   = (int)threadIdx.x;
    const int t     = tid & 63;
    const int grp   = __builtin_amdgcn_readfirstlane(tid >> 6); // wave-uniform

    __shared__ float sm_bins[NUM_S * NUM_T];        // [s][t]
    __shared__ float sm_cnt[(NUM_S + 1) * NUM_T];   // [c][t], row 64 = discard

    for (int i = tid; i < NUM_S * NUM_T; i += 512)       sm_bins[i] = 0.f;
    for (int i = tid; i < (NUM_S + 1) * NUM_T; i += 512) sm_cnt[i]  = 0.f;
    __syncthreads();

    const float v0t = v[2 * t];
    const float v1t = v[2 * t + 1];

    const int gbeg = starts[g];
    const int n    = starts[g + 1] - gbeg;
    const int cbeg = gbeg + (n * chunk) / CHUNKS;
    const int cend = gbeg + (n * (chunk + 1)) / CHUNKS;

    #pragma unroll 2
    for (int i = cbeg + grp; i < cend; i += 8) {
        const float2 p  = x[i];                         // wave-uniform address
        const float  nh = fmaf(p.x, v0t, p.y * v1t);
        const float  uc = ceilf(fmaf(nh, 31.5f, 29.925f)); // (nh+0.95)*31.5
        const int    sw = (int)uc;
        const float  b  = fmaf(nh, K, K);               // K*(nh+1)
        #pragma unroll
        for (int j = 0; j < 4; ++j) {
            const float ex  = fmaf(uc + (float)j, -KD, b); // K*(nh - lin_s)
            const float val = __builtin_amdgcn_rcpf(
                                  1.0f + __builtin_amdgcn_exp2f(ex));
            const int s = sw + j;
            if ((unsigned)s < (unsigned)NUM_S)
                atomicAdd(&sm_bins[(s << 6) + t], val);
        }
        const int c = min(max(sw + 4, 0), NUM_S);
        atomicAdd(&sm_cnt[(c << 6) + t], 1.0f);
    }
    __syncthreads();

    // inclusive prefix over c for each t (64 lanes busy, serial over 64 rows)
    if (tid < 64) {
        float run = 0.f;
        for (int s = 0; s < NUM_S; ++s) {
            run += sm_cnt[(s << 6) + tid];
            sm_cnt[(s << 6) + tid] = run;
        }
    }
    __syncthreads();

    float* og = out + (size_t)g * (NUM_S * NUM_T);
    #pragma unroll
    for (int k = 0; k < 8; ++k) {
        const int s   = grp * 8 + k;
        const int idx = (s << 6) + t;
        atomicAdd(&og[idx], sm_bins[idx] + sm_cnt[idx]);
    }
}

extern "C" void kernel_launch(void* const* d_in, const int* in_sizes, int n_in,
                              void* d_out, int out_size, void* d_ws, size_t ws_size,
                              hipStream_t stream) {
    const float2* x   = (const float2*)d_in[0];   // [N,2] f32
    const float*  v   = (const float*)d_in[1];    // [64,2] f32
    const int*    bat = (const int*)d_in[3];      // [N] i32 (sorted)
    float* out = (float*)d_out;                   // [128,64,64] f32
    const int n = in_sizes[3];

    int* starts = (int*)d_ws;                     // NUM_GRAPHS+1 ints

    hipMemsetAsync(d_out, 0, (size_t)out_size * sizeof(float), stream);
    seg_starts_kernel<<<1, 256, 0, stream>>>(bat, n, starts);
    ect_window_kernel<<<dim3(NUM_GRAPHS, CHUNKS), 512, 0, stream>>>(
        x, v, starts, out);
}

// Round 3
// 33.117 us; speedup vs baseline: 4.4126x; 4.4126x over previous
//
#include <hip/hip_runtime.h>

#define NUM_GRAPHS 128
#define NUM_T 64
#define NUM_S 64
#define CHUNKS 2

// starts[g] = first index n with batch[n] >= g, g in [0, NUM_GRAPHS].
__global__ void seg_starts_kernel(const int* __restrict__ batch, int n,
                                  int* __restrict__ starts) {
    int g = threadIdx.x;
    if (g > NUM_GRAPHS) return;
    int lo = 0, hi = n;
    while (lo < hi) {
        int mid = (lo + hi) >> 1;
        if (batch[mid] < g) lo = mid + 1; else hi = mid;
    }
    starts[g] = lo;
}

// Windowed-sigmoid ECT with NATIVE u32 atomics (fixed point, scale 2^20).
// sigmoid(200*(lin_s - nh)) is ~0 below / ~1 above a 4-step window:
//   s_w = ceil((nh + 0.95) * 31.5)  (first s with z >= -10)
//   s in [s_w, s_w+4): exact sigmoid -> bins (u32, value * 2^20)
//   s >= s_w+4: contributes 1.0      -> cnt[c] += 1, prefix-summed later
// out_u32[s][t] = bins[s][t] + (prefix_cnt[s][t] << 20), atomically added to
// d_out (as u32), converted in place to f32 by convert_kernel.
__global__ __launch_bounds__(512, 1) void ect_window_kernel(
    const float2* __restrict__ x, const float* __restrict__ v,
    const int* __restrict__ starts, unsigned* __restrict__ outu)
{
    constexpr float K     = 288.53900817779268f;  // 200 * log2(e)
    constexpr float KD    = 9.1599685135807200f;  // K * (2/63)
    constexpr float SCALE = 1048576.0f;           // 2^20
    const int g     = blockIdx.x;
    const int chunk = blockIdx.y;
    const int tid   = (int)threadIdx.x;
    const int t     = tid & 63;
    const int grp   = __builtin_amdgcn_readfirstlane(tid >> 6); // wave id, 0..7

    __shared__ unsigned sm_bins[NUM_S * NUM_T];        // [s][t] fixed-point
    __shared__ unsigned sm_cnt[(NUM_S + 1) * NUM_T];   // [c][t], row 64 = discard
    __shared__ unsigned sm_seg[8 * NUM_T];             // per-s-octet cnt sums

    for (int i = tid; i < NUM_S * NUM_T; i += 512)       sm_bins[i] = 0u;
    for (int i = tid; i < (NUM_S + 1) * NUM_T; i += 512) sm_cnt[i]  = 0u;
    __syncthreads();

    const float v0t = v[2 * t];
    const float v1t = v[2 * t + 1];

    const int gbeg = starts[g];
    const int n    = starts[g + 1] - gbeg;
    const int cbeg = gbeg + (n * chunk) / CHUNKS;
    const int cend = gbeg + (n * (chunk + 1)) / CHUNKS;

    // 4 points per wave-iteration; waves stride 32 points.
    for (int ibase = cbeg + grp * 4; ibase < cend; ibase += 32) {
        #pragma unroll
        for (int pp = 0; pp < 4; ++pp) {
            const int j = ibase + pp;
            if (j >= cend) break;                       // wave-uniform
            const float2 p  = x[j];
            const float  nh = fmaf(p.x, v0t, p.y * v1t);
            const float  uc = ceilf(fmaf(nh, 31.5f, 29.925f));
            const int    sw = (int)uc;
            const float  b  = fmaf(nh, K, K);           // K*(nh+1)
            #pragma unroll
            for (int jj = 0; jj < 4; ++jj) {
                const float ex  = fmaf(uc + (float)jj, -KD, b);
                const float val = __builtin_amdgcn_rcpf(
                                      1.0f + __builtin_amdgcn_exp2f(ex));
                const int s = sw + jj;
                if ((unsigned)s < (unsigned)NUM_S)
                    atomicAdd(&sm_bins[(s << 6) + t],
                              (unsigned)fmaf(val, SCALE, 0.5f));
            }
            const int c = min(max(sw + 4, 0), NUM_S);
            atomicAdd(&sm_cnt[(c << 6) + t], 1u);
        }
    }
    __syncthreads();

    // Prefix-sum cnt over s, parallel: thread (grp,t) owns s = grp*8 + {0..7}.
    unsigned pref[8];
    unsigned tot = 0;
    #pragma unroll
    for (int k = 0; k < 8; ++k) {
        tot += sm_cnt[(((grp << 3) + k) << 6) + t];
        pref[k] = tot;
    }
    sm_seg[(grp << 6) + t] = tot;
    __syncthreads();
    unsigned off = 0;
    #pragma unroll
    for (int q = 0; q < 8; ++q)
        if (q < grp) off += sm_seg[(q << 6) + t];

    unsigned* og = outu + (size_t)g * (NUM_S * NUM_T);
    #pragma unroll
    for (int k = 0; k < 8; ++k) {
        const int s   = (grp << 3) + k;
        const int idx = (s << 6) + t;
        atomicAdd(&og[idx], sm_bins[idx] + ((pref[k] + off) << 20));
    }
}

// In-place u32 fixed-point -> f32 conversion of d_out.
__global__ void convert_kernel(unsigned* __restrict__ buf, int n) {
    constexpr float INV_SCALE = 9.5367431640625e-07f; // 2^-20
    const int i = blockIdx.x * 256 + (int)threadIdx.x;
    if (i < n) {
        const unsigned u = buf[i];
        ((float*)buf)[i] = (float)u * INV_SCALE;
    }
}

extern "C" void kernel_launch(void* const* d_in, const int* in_sizes, int n_in,
                              void* d_out, int out_size, void* d_ws, size_t ws_size,
                              hipStream_t stream) {
    const float2* x   = (const float2*)d_in[0];   // [N,2] f32
    const float*  v   = (const float*)d_in[1];    // [64,2] f32
    const int*    bat = (const int*)d_in[3];      // [N] i32 (sorted)
    const int n = in_sizes[3];

    int* starts = (int*)d_ws;                     // NUM_GRAPHS+1 ints

    hipMemsetAsync(d_out, 0, (size_t)out_size * sizeof(float), stream);
    seg_starts_kernel<<<1, 256, 0, stream>>>(bat, n, starts);
    ect_window_kernel<<<dim3(NUM_GRAPHS, CHUNKS), 512, 0, stream>>>(
        x, (const float*)d_in[1], starts, (unsigned*)d_out);
    convert_kernel<<<(out_size + 255) / 256, 256, 0, stream>>>(
        (unsigned*)d_out, out_size);
}

// Round 4
// 26.160 us; speedup vs baseline: 5.5861x; 1.2659x over previous
//
#include <hip/hip_runtime.h>

#define NUM_GRAPHS 128
#define NUM_T 64
#define NUM_S 64

// Fully fused windowed-sigmoid ECT.
// Grid: (128 graphs) x (2 theta-halves). Block = 512 threads, owns the
// disjoint output slice out[g][0:64][th*32 : th*32+32] -> plain stores.
//
// Window math: sigmoid(200*(lin_s - nh)) ~ 0 below / ~ 1 above a 4-step
// transition window starting at s_w = ceil((nh + 0.95) * 31.5):
//   s in [s_w, s_w+4): exact sigmoid -> LDS bins (u32 fixed point, *2^20)
//   s >= s_w+4       : contributes 1 -> cnt[s_w+4]++, prefix-summed at end
// Truncation error <= ~800 * sigmoid(-10) ~ 0.04 (threshold is 14.56).
__global__ __launch_bounds__(512, 1) void ect_fused_kernel(
    const float2* __restrict__ x, const float* __restrict__ v,
    const int* __restrict__ batch, int n, float* __restrict__ out)
{
    constexpr float K         = 288.53900817779268f;   // 200 * log2(e)
    constexpr float KD        = 9.1599685135807200f;   // K * (2/63)
    constexpr float SCALE     = 1048576.0f;            // 2^20
    constexpr float INV_SCALE = 9.5367431640625e-07f;  // 2^-20

    const int g   = blockIdx.x;
    const int th  = blockIdx.y;
    const int tid = (int)threadIdx.x;
    const int lane = tid & 63;
    const int tl   = lane & 31;   // theta column within this half
    const int ph   = lane >> 5;   // which of 2 parallel points
    const int wv   = tid >> 6;    // wave id 0..7

    __shared__ unsigned sm_bins[NUM_S * 32];        // [s][tcol] fixed-point
    __shared__ unsigned sm_cnt[(NUM_S + 1) * 32];   // [c][tcol], row 64 = bin
    __shared__ unsigned sm_seg[16 * 32];            // 2nd-level prefix sums
    __shared__ int sh_cnt[4];

    for (int i = tid; i < NUM_S * 32; i += 512)       sm_bins[i] = 0u;
    for (int i = tid; i < (NUM_S + 1) * 32; i += 512) sm_cnt[i]  = 0u;
    if (tid < 4) sh_cnt[tid] = 0;
    __syncthreads();

    // ---- lane-parallel segment search: loA = #(batch < g), loB = #(< g+1)
    const int S = (n + 511) / 512;              // probe stride
    {
        const int pos = tid * S;
        const int val = (pos < n) ? batch[pos] : 0x7fffffff;
        const unsigned long long mA = __ballot(val < g);
        const unsigned long long mB = __ballot(val < g + 1);
        if ((tid & 63) == 0) {
            atomicAdd(&sh_cnt[0], (int)__popcll(mA));
            atomicAdd(&sh_cnt[1], (int)__popcll(mB));
        }
    }
    __syncthreads();
    const int cA = sh_cnt[0], cB = sh_cnt[1];
    const int baseA = (cA - 1) * S, baseB = (cB - 1) * S;
    {
        int a2 = 0, b2 = 0;
        for (int j = tid + 1; j <= S; j += 512) {
            if (cA >= 1) {
                const int p  = baseA + j;
                const int vv = (p < n) ? batch[p] : 0x7fffffff;
                a2 += (vv < g);
            }
            if (cB >= 1) {
                const int p  = baseB + j;
                const int vv = (p < n) ? batch[p] : 0x7fffffff;
                b2 += (vv < g + 1);
            }
        }
        // a2/b2 are 0/1 here (loop runs once for n<=262144) but sum anyway
        const unsigned long long mA = __ballot(a2 != 0);
        const unsigned long long mB = __ballot(b2 != 0);
        if ((tid & 63) == 0) {
            atomicAdd(&sh_cnt[2], (int)__popcll(mA));
            atomicAdd(&sh_cnt[3], (int)__popcll(mB));
        }
    }
    __syncthreads();
    const int loA = (cA == 0) ? 0 : baseA + 1 + sh_cnt[2];
    const int loB = (cB == 0) ? 0 : baseB + 1 + sh_cnt[3];

    // ---- main point loop
    const int t   = th * 32 + tl;
    const float v0t = v[2 * t];
    const float v1t = v[2 * t + 1];

    for (int ibase = loA + wv * 4; ibase < loB; ibase += 32) {
        #pragma unroll
        for (int k = 0; k < 2; ++k) {
            const int j = ibase + ph * 2 + k;
            if (j < loB) {
                const float2 p  = x[j];
                const float  nh = fmaf(p.x, v0t, p.y * v1t);
                const float  uc = ceilf(fmaf(nh, 31.5f, 29.925f));
                const int    sw = (int)uc;
                const float  b  = fmaf(nh, K, K);         // K*(nh+1)
                #pragma unroll
                for (int jj = 0; jj < 4; ++jj) {
                    const float ex  = fmaf(uc + (float)jj, -KD, b);
                    const float val = __builtin_amdgcn_rcpf(
                                          1.0f + __builtin_amdgcn_exp2f(ex));
                    const int s = sw + jj;
                    if ((unsigned)s < (unsigned)NUM_S)
                        atomicAdd(&sm_bins[(s << 5) + tl],
                                  (unsigned)fmaf(val, SCALE, 0.5f));
                }
                const int c = min(max(sw + 4, 0), NUM_S);
                atomicAdd(&sm_cnt[(c << 5) + tl], 1u);
            }
        }
    }
    __syncthreads();

    // ---- prefix-sum cnt over s, then fused convert + store
    const int col = tid & 31;
    const int row = tid >> 5;          // 0..15, owns s = row*4 + {0..3}
    unsigned pref[4];
    unsigned tot = 0;
    #pragma unroll
    for (int k = 0; k < 4; ++k) {
        tot += sm_cnt[(((row << 2) + k) << 5) + col];
        pref[k] = tot;
    }
    sm_seg[(row << 5) + col] = tot;
    __syncthreads();
    unsigned off = 0;
    #pragma unroll
    for (int q = 0; q < 15; ++q)
        if (q < row) off += sm_seg[(q << 5) + col];

    float* og = out + ((size_t)g * NUM_S) * NUM_T + th * 32 + col;
    #pragma unroll
    for (int k = 0; k < 4; ++k) {
        const int s = (row << 2) + k;
        og[(size_t)s * NUM_T] =
            (float)(pref[k] + off) +
            (float)sm_bins[(s << 5) + col] * INV_SCALE;
    }
}

extern "C" void kernel_launch(void* const* d_in, const int* in_sizes, int n_in,
                              void* d_out, int out_size, void* d_ws, size_t ws_size,
                              hipStream_t stream) {
    const float2* x   = (const float2*)d_in[0];   // [N,2] f32
    const float*  v   = (const float*)d_in[1];    // [64,2] f32
    const int*    bat = (const int*)d_in[3];      // [N] i32 (sorted)
    float* out = (float*)d_out;                   // [128,64,64] f32
    const int n = in_sizes[3];

    ect_fused_kernel<<<dim3(NUM_GRAPHS, 2), 512, 0, stream>>>(x, v, bat, n, out);
}

// Round 5
// 19.236 us; speedup vs baseline: 7.5968x; 1.3600x over previous
//
#include <hip/hip_runtime.h>

#define NUM_GRAPHS 128
#define NUM_T 64
#define NUM_S 64
#define TPB 8            // thetas per block
#define NTH (NUM_T/TPB)  // 8 theta-octet blocks per graph

// Fully fused windowed-sigmoid ECT, max-occupancy decomposition.
// Grid: (128 graphs) x (8 theta-octets). Block = 512 threads owns the
// disjoint slice out[g][0:64][th*8 : th*8+8] -> plain stores, no global
// atomics, no memset.
//
// Window math: sigmoid(200*(lin_s - nh)) ~ 0 below / ~ 1 above a 4-step
// transition window starting at s_w = ceil((nh + 0.95) * 31.5):
//   s in [s_w, s_w+4): exact sigmoid -> LDS bins (u32 fixed point, *2^20)
//   s >= s_w+4       : contributes 1 -> cnt[s_w+4]++, prefix-summed at end
// The 4 exponentials are geometric: e_{j+1} = e_j * 2^-KD (1 exp2 total).
__global__ __launch_bounds__(512, 8) void ect_fused_kernel(
    const float2* __restrict__ x, const float* __restrict__ v,
    const int* __restrict__ batch, int n, float* __restrict__ out)
{
    constexpr float K         = 288.53900817779268f;   // 200 * log2(e)
    constexpr float KD        = 9.1599685135807200f;   // K * (2/63)
    constexpr float EC        = 1.7481368e-03f;        // 2^-KD
    constexpr float SCALE     = 1048576.0f;            // 2^20
    constexpr float INV_SCALE = 9.5367431640625e-07f;  // 2^-20

    const int g   = blockIdx.x;
    const int th  = blockIdx.y;
    const int tid = (int)threadIdx.x;
    const int lane = tid & 63;
    const int tl   = lane & 7;    // theta column within octet
    const int pg   = lane >> 3;   // point-group 0..7
    const int wv   = tid >> 6;    // wave id 0..7

    __shared__ unsigned sm_bins[NUM_S * TPB];        // [s][tl] fixed-point
    __shared__ unsigned sm_cnt[(NUM_S + 1) * TPB];   // [c][tl], row 64 = bin
    __shared__ unsigned sm_seg[8 * TPB];             // per-s-octet cnt sums
    __shared__ int sh_cnt[4];

    for (int i = tid; i < NUM_S * TPB; i += 512)       sm_bins[i] = 0u;
    for (int i = tid; i < (NUM_S + 1) * TPB; i += 512) sm_cnt[i]  = 0u;
    if (tid < 4) sh_cnt[tid] = 0;
    __syncthreads();

    // ---- lane-parallel segment search: loA = #(batch < g), loB = #(< g+1)
    const int S = (n + 511) / 512;              // probe stride
    {
        const int pos = tid * S;
        const int val = (pos < n) ? batch[pos] : 0x7fffffff;
        const unsigned long long mA = __ballot(val < g);
        const unsigned long long mB = __ballot(val < g + 1);
        if ((tid & 63) == 0) {
            atomicAdd(&sh_cnt[0], (int)__popcll(mA));
            atomicAdd(&sh_cnt[1], (int)__popcll(mB));
        }
    }
    __syncthreads();
    const int cA = sh_cnt[0], cB = sh_cnt[1];
    const int baseA = (cA - 1) * S, baseB = (cB - 1) * S;
    {
        int a2 = 0, b2 = 0;
        for (int j = tid + 1; j <= S; j += 512) {
            if (cA >= 1) {
                const int p  = baseA + j;
                const int vv = (p < n) ? batch[p] : 0x7fffffff;
                a2 += (vv < g);
            }
            if (cB >= 1) {
                const int p  = baseB + j;
                const int vv = (p < n) ? batch[p] : 0x7fffffff;
                b2 += (vv < g + 1);
            }
        }
        const unsigned long long mA = __ballot(a2 != 0);
        const unsigned long long mB = __ballot(b2 != 0);
        if ((tid & 63) == 0) {
            atomicAdd(&sh_cnt[2], (int)__popcll(mA));
            atomicAdd(&sh_cnt[3], (int)__popcll(mB));
        }
    }
    __syncthreads();
    const int loA = (cA == 0) ? 0 : baseA + 1 + sh_cnt[2];
    const int loB = (cB == 0) ? 0 : baseB + 1 + sh_cnt[3];

    // ---- main point loop: 8 points x 8 thetas per wave-iteration
    const int t = th * TPB + tl;
    const float v0t = v[2 * t];
    const float v1t = v[2 * t + 1];

    for (int ibase = loA + wv * 8; ibase < loB; ibase += 64) {
        const int j   = ibase + pg;
        const int jc  = min(j, loB - 1);
        const float2 p = x[jc];                       // coalesced 64B / wave
        float nh = fmaf(p.x, v0t, p.y * v1t);
        if (j >= loB) nh = 1.0e4f;                    // poison -> no-op lane
        const float uc = ceilf(fmaf(nh, 31.5f, 29.925f));
        const int   sw = (int)uc;
        const float b  = fmaf(nh, K, K);              // K*(nh+1)
        float e = __builtin_amdgcn_exp2f(fmaf(uc, -KD, b)); // in (2^5.3,2^14.4]
        #pragma unroll
        for (int jj = 0; jj < 4; ++jj) {
            const float val = __builtin_amdgcn_rcpf(1.0f + e);
            const int s = sw + jj;
            if ((unsigned)s < (unsigned)NUM_S)
                atomicAdd(&sm_bins[(s << 3) + tl],
                          (unsigned)fmaf(val, SCALE, 0.5f));
            e *= EC;
        }
        const int c = min(max(sw + 4, 0), NUM_S);
        atomicAdd(&sm_cnt[(c << 3) + tl], 1u);
    }
    __syncthreads();

    // ---- prefix-sum cnt over s (2-level), fused convert + store
    if (tid < 64) {
        const int seg = tid >> 3, col = tid & 7;
        unsigned run = 0;
        #pragma unroll
        for (int k = 0; k < 8; ++k) {
            const int r = ((seg << 3) + k);
            run += sm_cnt[(r << 3) + col];
            sm_cnt[(r << 3) + col] = run;             // inclusive within seg
        }
        sm_seg[(seg << 3) + col] = run;
    }
    __syncthreads();

    const int s   = tid >> 3;
    const int col = tid & 7;
    const int seg = s >> 3;
    unsigned off = 0;
    #pragma unroll
    for (int q = 0; q < 7; ++q)
        if (q < seg) off += sm_seg[(q << 3) + col];

    out[((size_t)g * NUM_S + s) * NUM_T + th * TPB + col] =
        (float)(sm_cnt[(s << 3) + col] + off) +
        (float)sm_bins[(s << 3) + col] * INV_SCALE;
}

extern "C" void kernel_launch(void* const* d_in, const int* in_sizes, int n_in,
                              void* d_out, int out_size, void* d_ws, size_t ws_size,
                              hipStream_t stream) {
    const float2* x   = (const float2*)d_in[0];   // [N,2] f32
    const float*  v   = (const float*)d_in[1];    // [64,2] f32
    const int*    bat = (const int*)d_in[3];      // [N] i32 (sorted)
    float* out = (float*)d_out;                   // [128,64,64] f32
    const int n = in_sizes[3];

    ect_fused_kernel<<<dim3(NUM_GRAPHS, NTH), 512, 0, stream>>>(x, v, bat, n, out);
}

// Round 6
// 17.504 us; speedup vs baseline: 8.3484x; 1.0989x over previous
//
#include <hip/hip_runtime.h>

#define NUM_GRAPHS 128
#define NUM_T 64
#define NUM_S 64
#define TPB 8            // thetas per block
#define NTH (NUM_T/TPB)  // 8 theta-octet blocks per graph

// Fully fused windowed-sigmoid ECT, max-occupancy decomposition.
// Grid: (128 graphs) x (8 theta-octets). Block = 512 threads owns the
// disjoint slice out[g][0:64][th*8 : th*8+8] -> plain stores, no global
// atomics, no memset.
//
// Window math: sigmoid(200*(lin_s - nh)) ~ 0 below / ~ 1 above a 3-step
// transition window starting at s_w = ceil((nh + 0.95) * 31.5):
//   s in [s_w, s_w+3): exact sigmoid -> LDS bins (u32 fixed point, *2^20)
//   s >= s_w+3       : contributes 1 -> cnt[s_w+3]++, prefix-summed at end
//   (j=3 term has z >= 9.05, sigmoid >= 1-1.2e-4 -> folded into count)
// The exponentials are geometric: e_{j+1} = e_j * 2^-KD (1 exp2 total).
// sw is clamped to [-4, 64] and evals write unconditionally into a padded
// bins array (rows 0..70, real s at rows 4..67) -> no bounds checks.
__global__ __launch_bounds__(512, 8) void ect_fused_kernel(
    const float2* __restrict__ x, const float* __restrict__ v,
    const int* __restrict__ batch, int n, float* __restrict__ out)
{
    constexpr float K         = 288.53900817779268f;   // 200 * log2(e)
    constexpr float KD        = 9.1599685135807200f;   // K * (2/63)
    constexpr float EC        = 1.7481368e-03f;        // 2^-KD
    constexpr float SCALE     = 1048576.0f;            // 2^20
    constexpr float INV_SCALE = 9.5367431640625e-07f;  // 2^-20

    const int g   = blockIdx.x;
    const int th  = blockIdx.y;
    const int tid = (int)threadIdx.x;
    const int lane = tid & 63;
    const int tl   = lane & 7;    // theta column within octet
    const int pg   = lane >> 3;   // point-group 0..7
    const int wv   = tid >> 6;    // wave id 0..7

    __shared__ unsigned sm_bins[72 * TPB];           // [s+4][tl], rows 0..70
    __shared__ unsigned sm_cnt[(NUM_S + 1) * TPB];   // [c][tl], row 64 = bin
    __shared__ unsigned sm_seg[8 * TPB];             // per-s-octet cnt sums
    __shared__ int sh_cnt[4];

    for (int i = tid; i < 72 * TPB; i += 512)          sm_bins[i] = 0u;
    for (int i = tid; i < (NUM_S + 1) * TPB; i += 512) sm_cnt[i]  = 0u;
    if (tid < 4) sh_cnt[tid] = 0;
    __syncthreads();

    // ---- lane-parallel segment search: loA = #(batch < g), loB = #(< g+1)
    const int S = (n + 511) / 512;              // probe stride
    {
        const int pos = tid * S;
        const int val = (pos < n) ? batch[pos] : 0x7fffffff;
        const unsigned long long mA = __ballot(val < g);
        const unsigned long long mB = __ballot(val < g + 1);
        if ((tid & 63) == 0) {
            atomicAdd(&sh_cnt[0], (int)__popcll(mA));
            atomicAdd(&sh_cnt[1], (int)__popcll(mB));
        }
    }
    __syncthreads();
    const int cA = sh_cnt[0], cB = sh_cnt[1];
    const int baseA = (cA - 1) * S, baseB = (cB - 1) * S;
    {
        int a2 = 0, b2 = 0;
        for (int j = tid + 1; j <= S; j += 512) {
            if (cA >= 1) {
                const int p  = baseA + j;
                const int vv = (p < n) ? batch[p] : 0x7fffffff;
                a2 += (vv < g);
            }
            if (cB >= 1) {
                const int p  = baseB + j;
                const int vv = (p < n) ? batch[p] : 0x7fffffff;
                b2 += (vv < g + 1);
            }
        }
        const unsigned long long mA = __ballot(a2 != 0);
        const unsigned long long mB = __ballot(b2 != 0);
        if ((tid & 63) == 0) {
            atomicAdd(&sh_cnt[2], (int)__popcll(mA));
            atomicAdd(&sh_cnt[3], (int)__popcll(mB));
        }
    }
    __syncthreads();
    const int loA = (cA == 0) ? 0 : baseA + 1 + sh_cnt[2];
    const int loB = (cB == 0) ? 0 : baseB + 1 + sh_cnt[3];

    // ---- main point loop: 8 points x 8 thetas per wave-iteration
    const int t = th * TPB + tl;
    const float v0t = v[2 * t];
    const float v1t = v[2 * t + 1];

    for (int ibase = loA + wv * 8; ibase < loB; ibase += 64) {
        const int j   = ibase + pg;
        const int jc  = min(j, loB - 1);
        const float2 p = x[jc];                       // coalesced 64B / wave
        float nh = fmaf(p.x, v0t, p.y * v1t);
        if (j >= loB) nh = 1.0e4f;                    // poison -> no-op lane
        float uc = ceilf(fmaf(nh, 31.5f, 29.925f));   // (nh+0.95)*31.5
        uc = fminf(fmaxf(uc, -4.0f), 64.0f);          // clamp -> safe rows
        const int   sw = (int)uc;
        const float b  = fmaf(nh, K, K);              // K*(nh+1)
        float e = __builtin_amdgcn_exp2f(fmaf(uc, -KD, b));
        #pragma unroll
        for (int jj = 0; jj < 3; ++jj) {
            const float val = __builtin_amdgcn_rcpf(1.0f + e);
            atomicAdd(&sm_bins[((sw + 4 + jj) << 3) + tl],
                      (unsigned)fmaf(val, SCALE, 0.5f));
            e *= EC;
        }
        const int c = min(max(sw + 3, 0), NUM_S);
        atomicAdd(&sm_cnt[(c << 3) + tl], 1u);
    }
    __syncthreads();

    // ---- prefix-sum cnt over s (2-level), fused convert + store
    if (tid < 64) {
        const int seg = tid >> 3, col = tid & 7;
        unsigned run = 0;
        #pragma unroll
        for (int k = 0; k < 8; ++k) {
            const int r = ((seg << 3) + k);
            run += sm_cnt[(r << 3) + col];
            sm_cnt[(r << 3) + col] = run;             // inclusive within seg
        }
        sm_seg[(seg << 3) + col] = run;
    }
    __syncthreads();

    const int s   = tid >> 3;
    const int col = tid & 7;
    const int seg = s >> 3;
    unsigned off = 0;
    #pragma unroll
    for (int q = 0; q < 7; ++q)
        if (q < seg) off += sm_seg[(q << 3) + col];

    out[((size_t)g * NUM_S + s) * NUM_T + th * TPB + col] =
        (float)(sm_cnt[(s << 3) + col] + off) +
        (float)sm_bins[((s + 4) << 3) + col] * INV_SCALE;
}

extern "C" void kernel_launch(void* const* d_in, const int* in_sizes, int n_in,
                              void* d_out, int out_size, void* d_ws, size_t ws_size,
                              hipStream_t stream) {
    const float2* x   = (const float2*)d_in[0];   // [N,2] f32
    const float*  v   = (const float*)d_in[1];    // [64,2] f32
    const int*    bat = (const int*)d_in[3];      // [N] i32 (sorted)
    float* out = (float*)d_out;                   // [128,64,64] f32
    const int n = in_sizes[3];

    ect_fused_kernel<<<dim3(NUM_GRAPHS, NTH), 512, 0, stream>>>(x, v, bat, n, out);
}

// Round 8
// 16.007 us; speedup vs baseline: 9.1295x; 1.0936x over previous
//
#include <hip/hip_runtime.h>

#define NUM_GRAPHS 128
#define NUM_T 64
#define NUM_S 64
#define TPB 8            // thetas per block
#define NTH (NUM_T/TPB)  // 8 theta-octet blocks per graph
#define NROWS 72         // padded word rows; used r in [0, 67]

// Fully fused windowed-sigmoid ECT, centered 2-eval window + packed LDS atomics.
// Grid: (128 graphs) x (8 theta-octets). Block = 512 threads owns the
// disjoint slice out[g][0:64][th*8 : th*8+8] -> plain stores.
//
// z_s = 200*(lin_s - nh) = 6.349*(s - w), w = (nh+1)*31.5, sw = floor(w):
//   eval s=sw   : z in (-6.35, 0]   -> exact sigmoid
//   eval s=sw+1 : z in (0, 6.35]    -> exact sigmoid
//   s <  sw     : z <= -6.35, folds to 0 (err <= 1.74e-3/pt)
//   s >= sw+2   : z >  +6.35, folds to 1 (err <= 1.74e-3/pt) -> suffix count
// LDS word w[r] = {lo: bin (x 2^20) for s=r-2, hi: count, suffix from s=r-1}:
//   u32 ds_add  at word sw+2 lo     (+u0)
//   u64 ds_add  at word sw+3        (+u1 | 1<<32)   [bin s=sw+1 AND count]
// out[s] = lo[s+2]*2^-20 + prefix_{r<=s+1} hi[r].
__global__ __launch_bounds__(512, 8) void ect_fused_kernel(
    const float2* __restrict__ x, const float* __restrict__ v,
    const int* __restrict__ batch, int n, float* __restrict__ out)
{
    constexpr float K         = 288.53900817779268f;   // 200 * log2(e)
    constexpr float KD        = 9.1599685135807190f;   // K * (2/63)
    constexpr float EXP_KD    = 572.0390f;             // 2^KD = e^(400/63)
    constexpr float SCALE     = 1048576.0f;            // 2^20
    constexpr float INV_SCALE = 9.5367431640625e-07f;  // 2^-20

    const int g   = blockIdx.x;
    const int th  = blockIdx.y;
    const int tid = (int)threadIdx.x;
    const int lane = tid & 63;
    const int tl   = lane & 7;    // theta column within octet
    const int pg   = lane >> 3;   // point-group 0..7
    const int wv   = tid >> 6;    // wave id 0..7

    __shared__ unsigned long long sm_w[NROWS * TPB];  // [r][tl] {lo:bin, hi:cnt}
    __shared__ unsigned sm_seg[8 * TPB];              // per-9-row-segment hi sums
    __shared__ int sh_cnt[4];

    for (int i = tid; i < NROWS * TPB; i += 512) sm_w[i] = 0ull;
    if (tid < 4) sh_cnt[tid] = 0;
    __syncthreads();

    // ---- lane-parallel segment search: loA = #(batch < g), loB = #(< g+1)
    const int S = (n + 511) / 512;              // probe stride
    {
        const int pos = tid * S;
        const int val = (pos < n) ? batch[pos] : 0x7fffffff;
        const unsigned long long mA = __ballot(val < g);
        const unsigned long long mB = __ballot(val < g + 1);
        if ((tid & 63) == 0) {
            atomicAdd(&sh_cnt[0], (int)__popcll(mA));
            atomicAdd(&sh_cnt[1], (int)__popcll(mB));
        }
    }
    __syncthreads();
    const int cA = sh_cnt[0], cB = sh_cnt[1];
    const int baseA = (cA - 1) * S, baseB = (cB - 1) * S;
    {
        int a2 = 0, b2 = 0;
        for (int j = tid + 1; j <= S; j += 512) {
            if (cA >= 1) {
                const int p  = baseA + j;
                const int vv = (p < n) ? batch[p] : 0x7fffffff;
                a2 += (vv < g);
            }
            if (cB >= 1) {
                const int p  = baseB + j;
                const int vv = (p < n) ? batch[p] : 0x7fffffff;
                b2 += (vv < g + 1);
            }
        }
        const unsigned long long mA = __ballot(a2 != 0);
        const unsigned long long mB = __ballot(b2 != 0);
        if ((tid & 63) == 0) {
            atomicAdd(&sh_cnt[2], (int)__popcll(mA));
            atomicAdd(&sh_cnt[3], (int)__popcll(mB));
        }
    }
    __syncthreads();
    const int loA = (cA == 0) ? 0 : baseA + 1 + sh_cnt[2];
    const int loB = (cB == 0) ? 0 : baseB + 1 + sh_cnt[3];

    // ---- main point loop: 8 points x 8 thetas per wave-iteration
    const int t = th * TPB + tl;
    const float v0t = v[2 * t];
    const float v1t = v[2 * t + 1];

    for (int ibase = loA + wv * 8; ibase < loB; ibase += 64) {
        const int j   = ibase + pg;
        const int jc  = min(j, loB - 1);
        const float2 p = x[jc];                       // coalesced 64B / wave
        float nh = fmaf(p.x, v0t, p.y * v1t);
        if (j >= loB) nh = 1.0e4f;                    // poison -> invisible
        float uc = floorf(fmaf(nh, 31.5f, 31.5f));    // sw = floor((nh+1)*31.5)
        uc = fminf(fmaxf(uc, -2.0f), 64.0f);          // words in [0, 67]
        const int   sw = (int)uc;
        const float b  = fmaf(nh, K, K);              // K*(nh+1)
        // E0 = exp2(sw*KD - b) = e^{200*(lin_sw - nh)}, in (2^-9.16, 1] unclamped
        const float E0 = __builtin_amdgcn_exp2f(fmaf(uc, KD, -b));
        const float E1 = E0 * EXP_KD;
        // sigmoid = E/(1+E) = 1 - rcp(1+E); saturates 0/1 NaN-free at inf/0
        const float s0 = 1.0f - __builtin_amdgcn_rcpf(1.0f + E0);
        const float s1 = 1.0f - __builtin_amdgcn_rcpf(1.0f + E1);
        const unsigned u0 = (unsigned)fmaf(s0, SCALE, 0.5f);
        const unsigned u1 = (unsigned)fmaf(s1, SCALE, 0.5f);
        const int wi = ((sw + 2) << 3) + tl;           // word index of sw+2
        atomicAdd(&((unsigned*)sm_w)[wi << 1], u0);    // lo half, ds_add_u32
        atomicAdd(&sm_w[wi + TPB],                     // word sw+3, ds_add_u64
                  (unsigned long long)u1 | (1ULL << 32));
    }
    __syncthreads();

    // ---- Phase A: per-col inclusive prefix of hi within 9-row segments
    if (tid < 64) {
        const int seg = tid >> 3, col = tid & 7;
        const int r0 = seg * 9;
        unsigned run = 0;
        #pragma unroll
        for (int k = 0; k < 9; ++k) {
            const int idx = ((r0 + k) << 3) + col;
            const unsigned long long w = sm_w[idx];
            run += (unsigned)(w >> 32);
            sm_w[idx] = (w & 0xFFFFFFFFull) | ((unsigned long long)run << 32);
        }
        sm_seg[(seg << 3) + col] = run;
    }
    __syncthreads();

    // ---- Phase B: out[s] = lo[s+2]*eps + prefix_{r<=s+1} hi[r]
    const int s   = tid >> 3;
    const int col = tid & 7;
    const int ir  = s + 1;               // inclusive prefix row, 1..64
    const int seg_i = ir / 9;
    unsigned off = 0;
    #pragma unroll
    for (int q = 0; q < 7; ++q)
        if (q < seg_i) off += sm_seg[(q << 3) + col];

    const unsigned hi_pref = (unsigned)(sm_w[(ir << 3) + col] >> 32);
    const unsigned lo      = (unsigned)(sm_w[((s + 2) << 3) + col]);

    out[((size_t)g * NUM_S + s) * NUM_T + th * TPB + col] =
        (float)(off + hi_pref) + (float)lo * INV_SCALE;
}

extern "C" void kernel_launch(void* const* d_in, const int* in_sizes, int n_in,
                              void* d_out, int out_size, void* d_ws, size_t ws_size,
                              hipStream_t stream) {
    const float2* x   = (const float2*)d_in[0];   // [N,2] f32
    const float*  v   = (const float*)d_in[1];    // [64,2] f32
    const int*    bat = (const int*)d_in[3];      // [N] i32 (sorted)
    float* out = (float*)d_out;                   // [128,64,64] f32
    const int n = in_sizes[3];

    ect_fused_kernel<<<dim3(NUM_GRAPHS, NTH), 512, 0, stream>>>(x, v, bat, n, out);
}

// Round 9
// 15.993 us; speedup vs baseline: 9.1373x; 1.0009x over previous
//
#include <hip/hip_runtime.h>

#define NUM_GRAPHS 128
#define NUM_T 64
#define NUM_S 64
#define TPB 8            // thetas per block
#define NTH (NUM_T/TPB)  // 8 theta-octet blocks per graph
#define NROWS 68         // word rows wr = sw+2, sw in [-2,64] -> wr in [0,66]

// Fully fused windowed-sigmoid ECT, centered 2-eval window, ONE packed
// ds_add_u64 per (point,theta) pair.
// Grid: (128 graphs) x (8 theta-octets). Block = 512 threads owns the
// disjoint slice out[g][0:64][th*8 : th*8+8] -> plain stores.
//
// w = (nh+1)*31.5, sw = floor(w), f = w - sw in [0,1):
//   s = sw   : z0 = -6.349*f      in (-6.35, 0]  -> exact sigmoid
//   s = sw+1 : z1 = z0 + 6.349    in (0, 6.35]   -> exact sigmoid
//   s < sw   : folds to 0 (err <= 1.74e-3/pt)
//   s >= sw+2: folds to 1 (err <= 1.74e-3/pt)    -> suffix count
// Packed LDS word at row wr = sw+2 (one ds_add_u64):
//   bits[ 0:25) bin(s=wr-2) x 2^14   (sum <= 900*2^14 = 14.7M < 2^25)
//   bits[25:50) bin(s=wr-1) x 2^14
//   bits[50:64) count, suffix from s=wr  (<= 900 < 2^14)
// out[s] = (f0(w[s+2]) + f1(w[s+1]))*2^-14 + prefix_{wr<=s} cnt(w[wr]).
__global__ __launch_bounds__(512, 8) void ect_fused_kernel(
    const float2* __restrict__ x, const float* __restrict__ v,
    const int* __restrict__ batch, int n, float* __restrict__ out)
{
    constexpr float KD        = 9.1599685135807190f;   // 200*log2(e)*(2/63)
    constexpr float EXP_KD    = 572.03899f;            // 2^KD = e^(400/63)
    constexpr float SCALE     = 16384.0f;              // 2^14
    constexpr float INV_SCALE = 6.103515625e-05f;      // 2^-14
    constexpr unsigned M25    = 0x1FFFFFFu;

    const int g   = blockIdx.x;
    const int th  = blockIdx.y;
    const int tid = (int)threadIdx.x;
    const int lane = tid & 63;
    const int tl   = lane & 7;    // theta column within octet
    const int pg   = lane >> 3;   // point-group 0..7
    const int wv   = tid >> 6;    // wave id 0..7

    __shared__ unsigned long long sm_w[NROWS * TPB];  // [wr][tl] packed
    __shared__ unsigned sm_pref[NUM_S * TPB];         // inclusive cnt prefix
    __shared__ unsigned sm_seg[8 * TPB];              // per-8-row-segment sums
    __shared__ int sh_cnt[4];

    for (int i = tid; i < NROWS * TPB; i += 512) sm_w[i] = 0ull;
    if (tid < 4) sh_cnt[tid] = 0;
    __syncthreads();

    // ---- lane-parallel segment search: loA = #(batch < g), loB = #(< g+1)
    const int S = (n + 511) / 512;              // probe stride
    {
        const int pos = tid * S;
        const int val = (pos < n) ? batch[pos] : 0x7fffffff;
        const unsigned long long mA = __ballot(val < g);
        const unsigned long long mB = __ballot(val < g + 1);
        if ((tid & 63) == 0) {
            atomicAdd(&sh_cnt[0], (int)__popcll(mA));
            atomicAdd(&sh_cnt[1], (int)__popcll(mB));
        }
    }
    __syncthreads();
    const int cA = sh_cnt[0], cB = sh_cnt[1];
    const int baseA = (cA - 1) * S, baseB = (cB - 1) * S;
    {
        int a2 = 0, b2 = 0;
        for (int j = tid + 1; j <= S; j += 512) {
            if (cA >= 1) {
                const int p  = baseA + j;
                const int vv = (p < n) ? batch[p] : 0x7fffffff;
                a2 += (vv < g);
            }
            if (cB >= 1) {
                const int p  = baseB + j;
                const int vv = (p < n) ? batch[p] : 0x7fffffff;
                b2 += (vv < g + 1);
            }
        }
        const unsigned long long mA = __ballot(a2 != 0);
        const unsigned long long mB = __ballot(b2 != 0);
        if ((tid & 63) == 0) {
            atomicAdd(&sh_cnt[2], (int)__popcll(mA));
            atomicAdd(&sh_cnt[3], (int)__popcll(mB));
        }
    }
    __syncthreads();
    const int loA = (cA == 0) ? 0 : baseA + 1 + sh_cnt[2];
    const int loB = (cB == 0) ? 0 : baseB + 1 + sh_cnt[3];

    // ---- main point loop: 8 points x 8 thetas per wave-iteration
    const int t = th * TPB + tl;
    const float v0t = v[2 * t];
    const float v1t = v[2 * t + 1];

    for (int ibase = loA + wv * 8; ibase < loB; ibase += 64) {
        const int j   = ibase + pg;
        const int jc  = min(j, loB - 1);
        const float2 p = x[jc];                       // coalesced 64B / wave
        float nh = fmaf(p.x, v0t, p.y * v1t);
        if (j >= loB) nh = 1.0e4f;                    // poison -> discard rows
        const float w  = fmaf(nh, 31.5f, 31.5f);      // (nh+1)*31.5
        float uc = floorf(w);
        uc = fminf(fmaxf(uc, -2.0f), 64.0f);          // wr = uc+2 in [0,66]
        const float f  = w - uc;                      // in [0,1) unclamped
        // E0 = 2^(-KD*f) = e^{z0}; saturates to inf/0 at the clamps (NaN-free)
        const float E0 = __builtin_amdgcn_exp2f(-KD * f);
        const float E1 = E0 * EXP_KD;
        const float r0 = __builtin_amdgcn_rcpf(1.0f + E0);
        const float r1 = __builtin_amdgcn_rcpf(1.0f + E1);
        // u = round(sigmoid * 2^14), sigmoid = 1 - r
        const unsigned u0 = (unsigned)fmaf(r0, -SCALE, SCALE + 0.5f);
        const unsigned u1 = (unsigned)fmaf(r1, -SCALE, SCALE + 0.5f);
        const unsigned long long inc =
            (unsigned long long)u0 | ((unsigned long long)u1 << 25) |
            (1ULL << 50);
        const int wr = (int)uc + 2;
        atomicAdd(&sm_w[(wr << 3) + tl], inc);
    }
    __syncthreads();

    // ---- Phase A: per-col inclusive prefix of cnt field over wr = 0..63
    if (tid < 64) {
        const int seg = tid >> 3, col = tid & 7;
        unsigned run = 0;
        #pragma unroll
        for (int k = 0; k < 8; ++k) {
            const int wr = (seg << 3) + k;
            run += (unsigned)(sm_w[(wr << 3) + col] >> 50);
            sm_pref[(wr << 3) + col] = run;           // inclusive within seg
        }
        sm_seg[(seg << 3) + col] = run;
    }
    __syncthreads();

    // ---- Phase B: combine + store
    const int s   = tid >> 3;
    const int col = tid & 7;
    const int seg_i = s >> 3;
    unsigned off = 0;
    #pragma unroll
    for (int q = 0; q < 7; ++q)
        if (q < seg_i) off += sm_seg[(q << 3) + col];

    const unsigned long long w1 = sm_w[((s + 1) << 3) + col];
    const unsigned long long w2 = sm_w[((s + 2) << 3) + col];
    const unsigned bins = ((unsigned)w2 & M25) +
                          ((unsigned)(w1 >> 25) & M25);

    out[((size_t)g * NUM_S + s) * NUM_T + th * TPB + col] =
        (float)(off + sm_pref[(s << 3) + col]) + (float)bins * INV_SCALE;
}

extern "C" void kernel_launch(void* const* d_in, const int* in_sizes, int n_in,
                              void* d_out, int out_size, void* d_ws, size_t ws_size,
                              hipStream_t stream) {
    const float2* x   = (const float2*)d_in[0];   // [N,2] f32
    const float*  v   = (const float*)d_in[1];    // [64,2] f32
    const int*    bat = (const int*)d_in[3];      // [N] i32 (sorted)
    float* out = (float*)d_out;                   // [128,64,64] f32
    const int n = in_sizes[3];

    ect_fused_kernel<<<dim3(NUM_GRAPHS, NTH), 512, 0, stream>>>(x, v, bat, n, out);
}

// Round 10
// 14.757 us; speedup vs baseline: 9.9025x; 1.0837x over previous
//
#include <hip/hip_runtime.h>

#define NUM_GRAPHS 128
#define NUM_T 64
#define NUM_S 64
#define TPB 8            // thetas per block
#define NTH (NUM_T/TPB)  // 8 theta-octet blocks per graph
#define NROWS 66         // word rows wr = sw+1, sw in [-1,64] -> wr in [0,65]

// Fully fused windowed-sigmoid ECT, centered 1-eval window, one ds_add_u64
// per (point,theta) pair with a CONSTANT hi word.
// Grid: (128 graphs) x (8 theta-octets). Block = 512 threads owns the
// disjoint slice out[g][0:64][th*8 : th*8+8] -> plain stores.
//
// w = (nh+1)*31.5, sw = rint(w), d = sw - w in [-0.5, 0.5]:
//   s = sw   : z = -6.349*d in [-3.17, 3.17] -> exact sigmoid
//   s < sw   : z <= -3.17, folds to 0 (err <= 0.040/pt)
//   s > sw   : z >= +3.17, folds to 1 (err <= 0.040/pt) -> suffix count
// Packed LDS word at row wr = sw+1 (one ds_add_u64, hi word constant 1):
//   lo 32b: bin(s=wr-1) x 2^20   (sum <= 900*2^20 = 9.4e8 < 2^32, no carry)
//   hi 32b: count, suffix from s=wr   (<= 900)
// out[s] = lo(w[s+1])*2^-20 + prefix_{wr<=s} hi(w[wr]).
// Saturation is NaN-free at both clamps: w << 0 -> E=inf -> sig=1 into
// row 0 (bin s=-1 discarded, count covers all s>=0); w >> 64 -> E=0 ->
// sig=0 into row 65 (bin s=64 discarded, count suffix starts at s=65).
__global__ __launch_bounds__(512, 8) void ect_fused_kernel(
    const float2* __restrict__ x, const float* __restrict__ v,
    const int* __restrict__ batch, int n, float* __restrict__ out)
{
    constexpr float KD        = 9.1599685135807190f;   // 200*log2(e)*(2/63)
    constexpr float SCALE     = 1048576.0f;            // 2^20
    constexpr float INV_SCALE = 9.5367431640625e-07f;  // 2^-20

    const int g   = blockIdx.x;
    const int th  = blockIdx.y;
    const int tid = (int)threadIdx.x;
    const int lane = tid & 63;
    const int tl   = lane & 7;    // theta column within octet
    const int pg   = lane >> 3;   // point-group 0..7
    const int wv   = tid >> 6;    // wave id 0..7

    __shared__ unsigned long long sm_w[NROWS * TPB];  // [wr][tl] {lo:bin,hi:cnt}
    __shared__ unsigned sm_pref[NUM_S * TPB];         // inclusive cnt prefix
    __shared__ unsigned sm_seg[8 * TPB];              // per-8-row-segment sums
    __shared__ int sh_cnt[4];

    for (int i = tid; i < NROWS * TPB; i += 512) sm_w[i] = 0ull;
    if (tid < 4) sh_cnt[tid] = 0;
    __syncthreads();

    // ---- lane-parallel segment search: loA = #(batch < g), loB = #(< g+1)
    const int S = (n + 511) / 512;              // probe stride
    {
        const int pos = tid * S;
        const int val = (pos < n) ? batch[pos] : 0x7fffffff;
        const unsigned long long mA = __ballot(val < g);
        const unsigned long long mB = __ballot(val < g + 1);
        if ((tid & 63) == 0) {
            atomicAdd(&sh_cnt[0], (int)__popcll(mA));
            atomicAdd(&sh_cnt[1], (int)__popcll(mB));
        }
    }
    __syncthreads();
    const int cA = sh_cnt[0], cB = sh_cnt[1];
    const int baseA = (cA - 1) * S, baseB = (cB - 1) * S;
    {
        int a2 = 0, b2 = 0;
        for (int j = tid + 1; j <= S; j += 512) {
            if (cA >= 1) {
                const int p  = baseA + j;
                const int vv = (p < n) ? batch[p] : 0x7fffffff;
                a2 += (vv < g);
            }
            if (cB >= 1) {
                const int p  = baseB + j;
                const int vv = (p < n) ? batch[p] : 0x7fffffff;
                b2 += (vv < g + 1);
            }
        }
        const unsigned long long mA = __ballot(a2 != 0);
        const unsigned long long mB = __ballot(b2 != 0);
        if ((tid & 63) == 0) {
            atomicAdd(&sh_cnt[2], (int)__popcll(mA));
            atomicAdd(&sh_cnt[3], (int)__popcll(mB));
        }
    }
    __syncthreads();
    const int loA = (cA == 0) ? 0 : baseA + 1 + sh_cnt[2];
    const int loB = (cB == 0) ? 0 : baseB + 1 + sh_cnt[3];

    // ---- main point loop: 8 points x 8 thetas per wave-iteration
    const int t = th * TPB + tl;
    const float w0t = 31.5f * v[2 * t];
    const float w1t = 31.5f * v[2 * t + 1];

    for (int ibase = loA + wv * 8; ibase < loB; ibase += 64) {
        const int j   = ibase + pg;
        const int jc  = min(j, loB - 1);
        const float2 p = x[jc];                       // coalesced 64B / wave
        float w = fmaf(p.x, w0t, fmaf(p.y, w1t, 31.5f)); // (nh+1)*31.5
        if (j >= loB) w = 3.2e6f;                     // poison -> row 65
        float uc = rintf(w);                          // sw
        uc = fminf(fmaxf(uc, -1.0f), 64.0f);          // wr = uc+1 in [0,65]
        const float d  = uc - w;                      // in [-0.5, 0.5]
        // E = 2^(KD*d) = e^{z}, z = 200*(lin_sw - nh); saturates inf/0 at clamps
        const float E  = __builtin_amdgcn_exp2f(KD * d);
        const float r0 = __builtin_amdgcn_rcpf(1.0f + E);
        // u0 = round(sigmoid * 2^20), sigmoid = 1 - r0  (NaN-free: E=inf->1, E=0->0)
        const unsigned u0 = (unsigned)fmaf(r0, -SCALE, SCALE + 0.5f);
        const int wr = (int)uc + 1;
        atomicAdd(&sm_w[(wr << 3) + tl],
                  (unsigned long long)u0 | (1ULL << 32));
    }
    __syncthreads();

    // ---- Phase A: per-col inclusive prefix of cnt (hi word) over wr = 0..63
    if (tid < 64) {
        const int seg = tid >> 3, col = tid & 7;
        unsigned run = 0;
        #pragma unroll
        for (int k = 0; k < 8; ++k) {
            const int wr = (seg << 3) + k;
            run += (unsigned)(sm_w[(wr << 3) + col] >> 32);
            sm_pref[(wr << 3) + col] = run;           // inclusive within seg
        }
        sm_seg[(seg << 3) + col] = run;
    }
    __syncthreads();

    // ---- Phase B: combine + store. out[s] = bins(row s+1)*eps + cnt_prefix(s)
    const int s   = tid >> 3;
    const int col = tid & 7;
    const int seg_i = s >> 3;
    unsigned off = 0;
    #pragma unroll
    for (int q = 0; q < 7; ++q)
        if (q < seg_i) off += sm_seg[(q << 3) + col];

    const unsigned bins = (unsigned)sm_w[((s + 1) << 3) + col];

    out[((size_t)g * NUM_S + s) * NUM_T + th * TPB + col] =
        (float)(off + sm_pref[(s << 3) + col]) + (float)bins * INV_SCALE;
}

extern "C" void kernel_launch(void* const* d_in, const int* in_sizes, int n_in,
                              void* d_out, int out_size, void* d_ws, size_t ws_size,
                              hipStream_t stream) {
    const float2* x   = (const float2*)d_in[0];   // [N,2] f32
    const float*  v   = (const float*)d_in[1];    // [64,2] f32
    const int*    bat = (const int*)d_in[3];      // [N] i32 (sorted)
    float* out = (float*)d_out;                   // [128,64,64] f32
    const int n = in_sizes[3];

    ect_fused_kernel<<<dim3(NUM_GRAPHS, NTH), 512, 0, stream>>>(x, v, bat, n, out);
}

// Round 11
// 13.767 us; speedup vs baseline: 10.6146x; 1.0719x over previous
//
#include <hip/hip_runtime.h>

#define NUM_GRAPHS 128
#define NUM_T 64
#define NUM_S 64
#define TPB 8            // thetas per block
#define NTH (NUM_T/TPB)  // 8 theta-octet blocks per graph
#define NROWS 66         // word rows wr = sw+1, sw in [-1,64] -> wr in [0,65]

// Fully fused windowed-sigmoid ECT: centered 1-eval window, quintic
// polynomial sigmoid (no transcendentals), one ds_add_u64 per pair.
// Grid: (128 graphs) x (8 theta-octets). Block = 512 threads owns the
// disjoint slice out[g][0:64][th*8 : th*8+8] -> plain stores.
//
// w = (nh+1)*31.5, sw = rint(w), d = sw - w in [-0.5, 0.5] ALWAYS:
//   s = sw : z = -6.349*d in [-3.17, 3.17] -> sigma(z) ~= 0.5 + g(d),
//            g(d) = c1*d + c3*d^3 + c5*d^5 (odd quintic, |err| <= 0.0045)
//   s < sw : folds to 0 (err <= 0.040/pt);  s > sw : folds to 1 -> count
// LDS word at [tl][wr], wr = clamp(sw,-1,64)+1 (one ds_add_u64):
//   lo 32b: bin(s=wr-1) x 2^20  (u0 < 2^21, sum <= 900*2^21 < 2^32)
//   hi 32b: count, suffix from s=wr
// Rows 0 (bin s=-1) and 65 (count from s=65) are natural discards, so the
// clamped lanes' poly value never matters. [tl][wr] layout: atomic bank =
// (4*tl + 2*wr)%32 -> same-tl lanes conflict only at wr==wr' (mod 16).
__global__ __launch_bounds__(512, 8) void ect_fused_kernel(
    const float2* __restrict__ x, const float* __restrict__ v,
    const int* __restrict__ batch, int n, float* __restrict__ out)
{
    constexpr float C1 = 1.569095f;   // minimax-ish interp of 0.5*tanh(3.1746 d)
    constexpr float C3 = -4.224718f;
    constexpr float C5 = 6.509020f;
    constexpr float SCALE     = 1048576.0f;            // 2^20
    constexpr float HALFBIAS  = 524288.5f;             // 0.5*2^20 + 0.5 (round)
    constexpr float INV_SCALE = 9.5367431640625e-07f;  // 2^-20

    const int g   = blockIdx.x;
    const int th  = blockIdx.y;
    const int tid = (int)threadIdx.x;
    const int lane = tid & 63;
    const int tl   = lane & 7;    // theta column within octet
    const int pg   = lane >> 3;   // point-group 0..7
    const int wv   = tid >> 6;    // wave id 0..7

    __shared__ unsigned long long sm_w[TPB * NROWS];  // [tl][wr] {lo:bin,hi:cnt}
    __shared__ unsigned sm_pref[NUM_S * TPB];         // [s][col] incl. prefix
    __shared__ unsigned sm_seg[8 * TPB];              // per-8-row-segment sums
    __shared__ int sh_cnt[4];

    for (int i = tid; i < TPB * NROWS; i += 512) sm_w[i] = 0ull;
    if (tid < 4) sh_cnt[tid] = 0;
    __syncthreads();

    // ---- lane-parallel segment search: loA = #(batch < g), loB = #(< g+1)
    const int S = (n + 511) / 512;              // probe stride
    {
        const int pos = tid * S;
        const int val = (pos < n) ? batch[pos] : 0x7fffffff;
        const unsigned long long mA = __ballot(val < g);
        const unsigned long long mB = __ballot(val < g + 1);
        if ((tid & 63) == 0) {
            atomicAdd(&sh_cnt[0], (int)__popcll(mA));
            atomicAdd(&sh_cnt[1], (int)__popcll(mB));
        }
    }
    __syncthreads();
    const int cA = sh_cnt[0], cB = sh_cnt[1];
    const int baseA = (cA - 1) * S, baseB = (cB - 1) * S;
    {
        int a2 = 0, b2 = 0;
        for (int j = tid + 1; j <= S; j += 512) {
            if (cA >= 1) {
                const int p  = baseA + j;
                const int vv = (p < n) ? batch[p] : 0x7fffffff;
                a2 += (vv < g);
            }
            if (cB >= 1) {
                const int p  = baseB + j;
                const int vv = (p < n) ? batch[p] : 0x7fffffff;
                b2 += (vv < g + 1);
            }
        }
        const unsigned long long mA = __ballot(a2 != 0);
        const unsigned long long mB = __ballot(b2 != 0);
        if ((tid & 63) == 0) {
            atomicAdd(&sh_cnt[2], (int)__popcll(mA));
            atomicAdd(&sh_cnt[3], (int)__popcll(mB));
        }
    }
    __syncthreads();
    const int loA = (cA == 0) ? 0 : baseA + 1 + sh_cnt[2];
    const int loB = (cB == 0) ? 0 : baseB + 1 + sh_cnt[3];

    // ---- main point loop: 8 points x 8 thetas per wave-iteration
    const int t = th * TPB + tl;
    const float w0t = 31.5f * v[2 * t];
    const float w1t = 31.5f * v[2 * t + 1];
    const int tlBase1 = tl * NROWS + 1;   // hoisted: idx = tlBase1 + sw_clamped

    for (int ibase = loA + wv * 8; ibase < loB; ibase += 64) {
        const int j   = ibase + pg;
        const int jc  = min(j, loB - 1);
        const float2 p = x[jc];                       // coalesced 64B / wave
        float w = fmaf(p.x, w0t, fmaf(p.y, w1t, 31.5f)); // (nh+1)*31.5
        if (j >= loB) w = 3.2e6f;                     // poison -> row 65
        const float ucf = rintf(w);                   // sw (exact, |w|<2^24)
        const float d   = ucf - w;                    // in [-0.5, 0.5] ALWAYS
        // sigma - 0.5 ~= g(d), odd quintic (no exp2/rcp; max err 0.0045)
        const float t2 = d * d;
        const float pq = fmaf(fmaf(C5, t2, C3), t2, C1);
        const float gv = pq * d;                      // in [-0.46, 0.46]
        const unsigned u0 = (unsigned)fmaf(gv, SCALE, HALFBIAS);
        const int swi = max(min((int)ucf, 64), -1);   // addressing clamp only
        atomicAdd(&sm_w[tlBase1 + swi],
                  (unsigned long long)u0 | (1ULL << 32));
    }
    __syncthreads();

    // ---- Phase A: per-col inclusive prefix of cnt (hi word) over wr = 0..63
    if (tid < 64) {
        const int seg = tid >> 3, col = tid & 7;
        const int cb  = col * NROWS;
        unsigned run = 0;
        #pragma unroll
        for (int k = 0; k < 8; ++k) {
            const int wr = (seg << 3) + k;
            run += (unsigned)(sm_w[cb + wr] >> 32);
            sm_pref[(wr << 3) + col] = run;           // inclusive within seg
        }
        sm_seg[(seg << 3) + col] = run;
    }
    __syncthreads();

    // ---- Phase B: combine + store. out[s] = bins(wr=s+1)*eps + cnt_prefix(s)
    const int s   = tid >> 3;
    const int col = tid & 7;
    const int seg_i = s >> 3;
    unsigned off = 0;
    #pragma unroll
    for (int q = 0; q < 7; ++q)
        if (q < seg_i) off += sm_seg[(q << 3) + col];

    const unsigned bins = (unsigned)sm_w[col * NROWS + (s + 1)];

    out[((size_t)g * NUM_S + s) * NUM_T + th * TPB + col] =
        (float)(off + sm_pref[(s << 3) + col]) + (float)bins * INV_SCALE;
}

extern "C" void kernel_launch(void* const* d_in, const int* in_sizes, int n_in,
                              void* d_out, int out_size, void* d_ws, size_t ws_size,
                              hipStream_t stream) {
    const float2* x   = (const float2*)d_in[0];   // [N,2] f32
    const float*  v   = (const float*)d_in[1];    // [64,2] f32
    const int*    bat = (const int*)d_in[3];      // [N] i32 (sorted)
    float* out = (float*)d_out;                   // [128,64,64] f32
    const int n = in_sizes[3];

    ect_fused_kernel<<<dim3(NUM_GRAPHS, NTH), 512, 0, stream>>>(x, v, bat, n, out);
}